// Round 4
// baseline (94.366 us; speedup 1.0000x reference)
//
#include <hip/hip_runtime.h>
#include <hip/hip_bf16.h>

// proto_net_loss, all-MFMA:
//  prep:   W1T/W2T = bf16 transposed weights (L2-resident)
//  gemm1:  H(bf16) = X @ W1 via MFMA (1-wave blocks, grid 640) + per-16-row BN partials
//  final:  BN scale/shift per set (1024-thr tree)
//  gemm2:  Z(bf16) = relu(H*sc+sh) @ W2 via MFMA + f32 row norms (1-wave blocks)
//  dist:   D = n1[i] + n2[j] - 2 * Z1 @ Z2^T via MFMA, float4 epilogue (swapped operands)

#define LAT 512
#define HID 128
#define EPSV 1e-5f

typedef __attribute__((ext_vector_type(8))) short bf16x8;
typedef __attribute__((ext_vector_type(4))) float f32x4;

__device__ inline unsigned short f2bf(float x) {  // RTNE
  unsigned int u = __builtin_bit_cast(unsigned int, x);
  return (unsigned short)((u + 0x7fffu + ((u >> 16) & 1u)) >> 16);
}
__device__ inline float bf2f(unsigned short h) {
  unsigned int u = ((unsigned int)h) << 16;
  return __builtin_bit_cast(float, u);
}

// ---------------- prep: transpose weights to bf16 ----------------
__global__ __launch_bounds__(256) void k_prep(const float* __restrict__ W1,
                                              const float* __restrict__ W2,
                                              unsigned short* __restrict__ W1T,
                                              unsigned short* __restrict__ W2T) {
  const int t = blockIdx.x * 256 + threadIdx.x;
  if (t < LAT * HID) {
    const int n = t >> 9, k = t & 511;  // W1T[n][k] = W1[k][n]
    W1T[t] = f2bf(W1[(size_t)k * HID + n]);
  } else {
    const int t2 = t - LAT * HID;
    if (t2 < HID * HID) {
      const int n = t2 >> 7, k = t2 & 127;
      W2T[t2] = f2bf(W2[(size_t)k * HID + n]);
    }
  }
}

// ---------------- gemm1: 1 wave = 16 rows x 128 cols, K=512 ----------------
__global__ __launch_bounds__(64) void k_gemm1(
    const float* __restrict__ X1, const float* __restrict__ X2, int nx,
    const unsigned short* __restrict__ W1T, unsigned short* __restrict__ H,
    float* __restrict__ pS1, float* __restrict__ pQ1,
    float* __restrict__ pS2, float* __restrict__ pQ2, int nb1) {
  __shared__ float sS[4][HID], sQ[4][HID];
  const int lane = threadIdx.x;
  const int l15 = lane & 15, lq = lane >> 4, lk8 = lq * 8;
  const int row0 = (int)blockIdx.x * 16;
  const bool set1 = (int)blockIdx.x < nb1;
  const float* X = set1 ? X1 : X2;
  const int xrow = set1 ? row0 : row0 - nx;
  const float* xptr = X + (size_t)(xrow + l15) * LAT + lk8;
  f32x4 acc[8];
#pragma unroll
  for (int f = 0; f < 8; ++f) acc[f] = (f32x4){0.f, 0.f, 0.f, 0.f};

#pragma unroll
  for (int kb = 0; kb < LAT; kb += 128) {
    float4 xv[4][2];
#pragma unroll
    for (int s = 0; s < 4; ++s) {
      xv[s][0] = *(const float4*)(xptr + kb + s * 32);
      xv[s][1] = *(const float4*)(xptr + kb + s * 32 + 4);
    }
#pragma unroll
    for (int s = 0; s < 4; ++s) {
      const float vv[8] = {xv[s][0].x, xv[s][0].y, xv[s][0].z, xv[s][0].w,
                           xv[s][1].x, xv[s][1].y, xv[s][1].z, xv[s][1].w};
      bf16x8 bfr;
#pragma unroll
      for (int i = 0; i < 8; ++i) bfr[i] = (short)f2bf(vv[i]);
      const int k = kb + s * 32 + lk8;
#pragma unroll
      for (int f = 0; f < 8; ++f) {
        const bf16x8 afr = *(const bf16x8*)(W1T + (size_t)(f * 16 + l15) * LAT + k);
        acc[f] = __builtin_amdgcn_mfma_f32_16x16x32_bf16(afr, bfr, acc[f], 0, 0, 0);
      }
    }
  }
  // H[m=row0+l15][n=f*16+lq*4+r] (swapped layout -> ushort4 row-major store)
#pragma unroll
  for (int f = 0; f < 8; ++f) {
    ushort4 hz = {f2bf(acc[f][0]), f2bf(acc[f][1]), f2bf(acc[f][2]), f2bf(acc[f][3])};
    *(ushort4*)(H + (size_t)(row0 + l15) * HID + f * 16 + lq * 4) = hz;
  }
  // partial stats over the wave's 16 rows: 2 shfl stages + 4-row LDS fold
#pragma unroll
  for (int f = 0; f < 8; ++f) {
    f32x4 s = acc[f];
    f32x4 q = acc[f] * acc[f];
#pragma unroll
    for (int r = 0; r < 4; ++r) {
      s[r] += __shfl_xor(s[r], 1, 64);
      q[r] += __shfl_xor(q[r], 1, 64);
      s[r] += __shfl_xor(s[r], 2, 64);
      q[r] += __shfl_xor(q[r], 2, 64);
    }
    if ((l15 & 3) == 0) {
      *(f32x4*)&sS[l15 >> 2][f * 16 + lq * 4] = s;
      *(f32x4*)&sQ[l15 >> 2][f * 16 + lq * 4] = q;
    }
  }
  __syncthreads();
  {
    const int c0 = lane << 1;
    float2 sv, qv;
    sv.x = sS[0][c0] + sS[1][c0] + sS[2][c0] + sS[3][c0];
    sv.y = sS[0][c0 + 1] + sS[1][c0 + 1] + sS[2][c0 + 1] + sS[3][c0 + 1];
    qv.x = sQ[0][c0] + sQ[1][c0] + sQ[2][c0] + sQ[3][c0];
    qv.y = sQ[0][c0 + 1] + sQ[1][c0 + 1] + sQ[2][c0 + 1] + sQ[3][c0 + 1];
    float* pS = set1 ? pS1 + (size_t)blockIdx.x * HID
                     : pS2 + (size_t)((int)blockIdx.x - nb1) * HID;
    float* pQ = set1 ? pQ1 + (size_t)blockIdx.x * HID
                     : pQ2 + (size_t)((int)blockIdx.x - nb1) * HID;
    *(float2*)(pS + c0) = sv;
    *(float2*)(pQ + c0) = qv;
  }
}

// ---------------- finalize BN affine per set ----------------
__global__ __launch_bounds__(1024) void k_finalize(
    const float* __restrict__ pS1, const float* __restrict__ pQ1,
    const float* __restrict__ pS2, const float* __restrict__ pQ2,
    const float* __restrict__ gamma, const float* __restrict__ beta,
    float* __restrict__ sc1, float* __restrict__ sh1,
    float* __restrict__ sc2, float* __restrict__ sh2,
    int nb1, int nb2, float n1count, float n2count) {
  __shared__ float sA[8][HID], qA[8][HID], sB[2][HID], qB[2][HID];
  const int tid = threadIdx.x;
  const int col = tid & 127, chunk = tid >> 7;  // 0..7
  {
    const int len = nb1 >> 3;  // 64
    const int b0 = chunk * len;
    float s = 0.f, q = 0.f;
    for (int b = b0; b < b0 + len; ++b) {
      s += pS1[(size_t)b * HID + col];
      q += pQ1[(size_t)b * HID + col];
    }
    sA[chunk][col] = s;
    qA[chunk][col] = q;
  }
  if (chunk < 2) {
    const int len = nb2 >> 1;  // 64
    const int b0 = chunk * len;
    float s = 0.f, q = 0.f;
    for (int b = b0; b < b0 + len; ++b) {
      s += pS2[(size_t)b * HID + col];
      q += pQ2[(size_t)b * HID + col];
    }
    sB[chunk][col] = s;
    qB[chunk][col] = q;
  }
  __syncthreads();
  if (tid < 256) {
    const int c = tid & 127;
    const bool one = tid < 128;
    float s = 0.f, q = 0.f;
    if (one) {
#pragma unroll
      for (int r = 0; r < 8; ++r) { s += sA[r][c]; q += qA[r][c]; }
    } else {
      s = sB[0][c] + sB[1][c];
      q = qB[0][c] + qB[1][c];
    }
    const float n = one ? n1count : n2count;
    const float mean = s / n;
    const float var = q / n - mean * mean;
    const float rstd = rsqrtf(var + EPSV);
    const float scale = gamma[c] * rstd;
    const float shift = beta[c] - mean * scale;
    if (one) { sc1[c] = scale; sh1[c] = shift; }
    else     { sc2[c] = scale; sh2[c] = shift; }
  }
}

// ---------------- gemm2: Z(bf16) = relu(H*sc+sh) @ W2 + f32 row norms ----------------
__global__ __launch_bounds__(64) void k_gemm2(
    const unsigned short* __restrict__ H, int nx,
    const unsigned short* __restrict__ W2T,
    const float* __restrict__ sc1, const float* __restrict__ sh1,
    const float* __restrict__ sc2, const float* __restrict__ sh2,
    unsigned short* __restrict__ Z, float* __restrict__ nrm) {
  const int lane = threadIdx.x;
  const int l15 = lane & 15, lq = lane >> 4, lk8 = lq * 8;
  const int row0 = (int)blockIdx.x * 16;
  const bool set1 = row0 < nx;
  const float* sc = set1 ? sc1 : sc2;
  const float* sh = set1 ? sh1 : sh2;
  const unsigned short* hptr = H + (size_t)(row0 + l15) * HID + lk8;
  f32x4 acc[8];
#pragma unroll
  for (int f = 0; f < 8; ++f) acc[f] = (f32x4){0.f, 0.f, 0.f, 0.f};
#pragma unroll
  for (int s = 0; s < 4; ++s) {
    const int k = s * 32 + lk8;
    const bf16x8 hv = *(const bf16x8*)(hptr + s * 32);
    const float4 c0 = *(const float4*)(sc + k);
    const float4 c1 = *(const float4*)(sc + k + 4);
    const float4 d0 = *(const float4*)(sh + k);
    const float4 d1 = *(const float4*)(sh + k + 4);
    const float cc[8] = {c0.x, c0.y, c0.z, c0.w, c1.x, c1.y, c1.z, c1.w};
    const float dd[8] = {d0.x, d0.y, d0.z, d0.w, d1.x, d1.y, d1.z, d1.w};
    bf16x8 bfr;
#pragma unroll
    for (int i = 0; i < 8; ++i) {
      const float a = fmaxf(fmaf(bf2f((unsigned short)hv[i]), cc[i], dd[i]), 0.f);
      bfr[i] = (short)f2bf(a);
    }
#pragma unroll
    for (int f = 0; f < 8; ++f) {
      const bf16x8 afr = *(const bf16x8*)(W2T + (size_t)(f * 16 + l15) * HID + k);
      acc[f] = __builtin_amdgcn_mfma_f32_16x16x32_bf16(afr, bfr, acc[f], 0, 0, 0);
    }
  }
  float rn = 0.f;
#pragma unroll
  for (int f = 0; f < 8; ++f) {
    rn += acc[f][0] * acc[f][0] + acc[f][1] * acc[f][1] +
          acc[f][2] * acc[f][2] + acc[f][3] * acc[f][3];
    ushort4 z4 = {f2bf(acc[f][0]), f2bf(acc[f][1]), f2bf(acc[f][2]), f2bf(acc[f][3])};
    *(ushort4*)(Z + (size_t)(row0 + l15) * HID + f * 16 + lq * 4) = z4;
  }
  rn += __shfl_xor(rn, 16, 64);
  rn += __shfl_xor(rn, 32, 64);
  if (lane < 16) nrm[row0 + l15] = rn;
}

// ---------------- dist: D = n1[i] + n2[j] - 2 * Z1 @ Z2^T, float4 epilogue ----------------
// Swapped operands: mfma(Z2frag, Z1frag) -> lane holds D[row=.. + l15][col quad = lq*4 + r].
__global__ __launch_bounds__(256) void k_dist(const unsigned short* __restrict__ Z1b,
                                              const unsigned short* __restrict__ Z2b,
                                              const float* __restrict__ n1,
                                              const float* __restrict__ n2,
                                              float* __restrict__ D, int NY) {
  const int tid = threadIdx.x;
  const int wid = tid >> 6, lane = tid & 63;
  const int wr = wid >> 1, wc = wid & 1;
  const int rowB = blockIdx.y * 128 + wr * 64;
  const int colB = blockIdx.x * 128 + wc * 64;
  const int l15 = lane & 15, lq = lane >> 4;
  const int lk = lq * 8;
  const unsigned short* Arow = Z1b + (size_t)(rowB + l15) * HID + lk;
  const unsigned short* Brow = Z2b + (size_t)(colB + l15) * HID + lk;
  f32x4 acc[4][4];
#pragma unroll
  for (int i = 0; i < 4; ++i)
#pragma unroll
    for (int j = 0; j < 4; ++j) acc[i][j] = (f32x4){0.f, 0.f, 0.f, 0.f};
#pragma unroll
  for (int s = 0; s < 4; ++s) {
    bf16x8 a[4], b[4];
#pragma unroll
    for (int i = 0; i < 4; ++i) a[i] = *(const bf16x8*)(Arow + (size_t)i * 16 * HID + s * 32);
#pragma unroll
    for (int j = 0; j < 4; ++j) b[j] = *(const bf16x8*)(Brow + (size_t)j * 16 * HID + s * 32);
#pragma unroll
    for (int i = 0; i < 4; ++i)
#pragma unroll
      for (int j = 0; j < 4; ++j)
        acc[i][j] = __builtin_amdgcn_mfma_f32_16x16x32_bf16(b[j], a[i], acc[i][j], 0, 0, 0);
  }
  // lane holds D[rowB + i*16 + l15][colB + j*16 + lq*4 + r], r=0..3
  const int cq = lq * 4;
  float na[4];
#pragma unroll
  for (int i = 0; i < 4; ++i) na[i] = n1[rowB + i * 16 + l15];
#pragma unroll
  for (int j = 0; j < 4; ++j) {
    const float4 nb = *(const float4*)(n2 + colB + j * 16 + cq);
#pragma unroll
    for (int i = 0; i < 4; ++i) {
      float4 o;
      o.x = na[i] + nb.x - 2.f * acc[i][j][0];
      o.y = na[i] + nb.y - 2.f * acc[i][j][1];
      o.z = na[i] + nb.z - 2.f * acc[i][j][2];
      o.w = na[i] + nb.w - 2.f * acc[i][j][3];
      *(float4*)(D + (size_t)(rowB + i * 16 + l15) * NY + colB + j * 16 + cq) = o;
    }
  }
}

extern "C" void kernel_launch(void* const* d_in, const int* in_sizes, int n_in,
                              void* d_out, int out_size, void* d_ws, size_t ws_size,
                              hipStream_t stream) {
  const float* variations = (const float*)d_in[0];
  const float* exemplar   = (const float*)d_in[1];
  const float* w1         = (const float*)d_in[2];
  const float* gamma      = (const float*)d_in[3];
  const float* beta       = (const float*)d_in[4];
  const float* w2         = (const float*)d_in[5];
  float* D = (float*)d_out;

  const int nx = in_sizes[0] / LAT;  // 8192
  const int ny = in_sizes[1] / LAT;  // 2048
  const int nrows = nx + ny;         // 10240
  const int nb1 = nx / 16;           // 512
  const int nb2 = ny / 16;           // 128
  const int nbb = nb1 + nb2;         // 640

  char* p = (char*)d_ws;
  unsigned short* Hb  = (unsigned short*)p; p += (size_t)nrows * HID * 2;
  unsigned short* Zb  = (unsigned short*)p; p += (size_t)nrows * HID * 2;
  unsigned short* W1T = (unsigned short*)p; p += (size_t)LAT * HID * 2;
  unsigned short* W2T = (unsigned short*)p; p += (size_t)HID * HID * 2;
  float* pS1 = (float*)p; p += (size_t)nb1 * HID * 4;
  float* pQ1 = (float*)p; p += (size_t)nb1 * HID * 4;
  float* pS2 = (float*)p; p += (size_t)nb2 * HID * 4;
  float* pQ2 = (float*)p; p += (size_t)nb2 * HID * 4;
  float* sc1 = (float*)p; p += HID * 4;
  float* sh1 = (float*)p; p += HID * 4;
  float* sc2 = (float*)p; p += HID * 4;
  float* sh2 = (float*)p; p += HID * 4;
  float* nrmAll = (float*)p; p += (size_t)nrows * 4;
  float* n1v = nrmAll;
  float* n2v = nrmAll + nx;
  unsigned short* Z1b = Zb;
  unsigned short* Z2b = Zb + (size_t)nx * HID;

  k_prep<<<(LAT * HID + HID * HID) / 256, 256, 0, stream>>>(w1, w2, W1T, W2T);
  k_gemm1<<<nbb, 64, 0, stream>>>(variations, exemplar, nx, W1T, Hb,
                                  pS1, pQ1, pS2, pQ2, nb1);
  k_finalize<<<1, 1024, 0, stream>>>(pS1, pQ1, pS2, pQ2, gamma, beta,
                                     sc1, sh1, sc2, sh2, nb1, nb2, (float)nx, (float)ny);
  k_gemm2<<<nbb, 64, 0, stream>>>(Hb, nx, W2T, sc1, sh1, sc2, sh2, Zb, nrmAll);
  dim3 dgrid(ny / 128, nx / 128);
  k_dist<<<dgrid, 256, 0, stream>>>(Z1b, Z2b, n1v, n2v, D, ny);
}

// Round 5
// 91.952 us; speedup vs baseline: 1.0263x; 1.0263x over previous
//
#include <hip/hip_runtime.h>
#include <hip/hip_bf16.h>

// proto_net_loss, all-MFMA:
//  prep:   W1T/W2T = bf16 transposed weights (LDS-tiled transpose, coalesced)
//  gemm1:  H(bf16) = X @ W1; 4 waves/block K-split (K=128 each) + LDS combine;
//          fused per-16-row BN partial stats. 640 blocks -> 2560 waves.
//  final:  BN scale/shift per set
//  gemm2:  Z(bf16) = relu(H*sc+sh) @ W2; 4 waves/block frag-split + f32 row norms.
//  dist:   D = n1[i] + n2[j] - 2 * Z1 @ Z2^T; swapped-operand MFMA, float4 stores.

#define LAT 512
#define HID 128
#define EPSV 1e-5f

typedef __attribute__((ext_vector_type(8))) short bf16x8;
typedef __attribute__((ext_vector_type(4))) float f32x4;

__device__ inline unsigned short f2bf(float x) {  // RTNE
  unsigned int u = __builtin_bit_cast(unsigned int, x);
  return (unsigned short)((u + 0x7fffu + ((u >> 16) & 1u)) >> 16);
}
__device__ inline float bf2f(unsigned short h) {
  unsigned int u = ((unsigned int)h) << 16;
  return __builtin_bit_cast(float, u);
}

// ---------------- prep: tiled transpose f32 -> bf16 (both sides coalesced) ----------------
// W1 (512x128) -> W1T (128x512): 8x2 = 16 tiles of 64x64. W2 (128x128) -> W2T: 4 tiles.
__global__ __launch_bounds__(256) void k_prep(const float* __restrict__ W1,
                                              const float* __restrict__ W2,
                                              unsigned short* __restrict__ W1T,
                                              unsigned short* __restrict__ W2T) {
  __shared__ float T[64][65];
  const int t = threadIdx.x;
  int bi = blockIdx.x;
  const float* src;
  unsigned short* dst;
  int K, N, tk, tn;
  if (bi < 16) { src = W1; dst = W1T; K = LAT; N = HID; tk = bi >> 1; tn = bi & 1; }
  else { bi -= 16; src = W2; dst = W2T; K = HID; N = HID; tk = bi >> 1; tn = bi & 1; }
  const int k0 = tk * 64, n0 = tn * 64;
  {
    const int rr = t >> 4, cc = (t & 15) * 4;
#pragma unroll
    for (int i = 0; i < 4; ++i) {
      const int r = rr + i * 16;
      const float4 v = *(const float4*)(src + (size_t)(k0 + r) * N + n0 + cc);
      T[cc + 0][r] = v.x; T[cc + 1][r] = v.y; T[cc + 2][r] = v.z; T[cc + 3][r] = v.w;
    }
  }
  __syncthreads();
  {
    const int nn = t >> 2, q = (t & 3) * 16;
    unsigned short* dp = dst + (size_t)(n0 + nn) * K + k0 + q;
#pragma unroll
    for (int j = 0; j < 4; ++j) {
      ushort4 o = {f2bf(T[nn][q + j * 4 + 0]), f2bf(T[nn][q + j * 4 + 1]),
                   f2bf(T[nn][q + j * 4 + 2]), f2bf(T[nn][q + j * 4 + 3])};
      *(ushort4*)(dp + j * 4) = o;
    }
  }
}

// ---------------- gemm1: 4 waves K-split over one 16-row strip ----------------
// wave w handles K chunk [w*128, w*128+128); partials combined in LDS.
// partial layout: part[w][lane' = lq*16 + row][f*4 + e]  (pad 33 -> 2-way free)
__global__ __launch_bounds__(256) void k_gemm1(
    const float* __restrict__ X1, const float* __restrict__ X2, int nx,
    const unsigned short* __restrict__ W1T, unsigned short* __restrict__ H,
    float* __restrict__ pS1, float* __restrict__ pQ1,
    float* __restrict__ pS2, float* __restrict__ pQ2, int nb1) {
  __shared__ float part[4][64][33];
  const int tid = threadIdx.x, w = tid >> 6, lane = tid & 63;
  const int l15 = lane & 15, lq = lane >> 4, lk8 = lq * 8;
  const int b = (int)blockIdx.x;
  const int row0 = b * 16;
  const bool set1 = b < nb1;
  const float* X = set1 ? X1 : X2;
  const int xrow = set1 ? row0 : row0 - nx;
  const int kb = w * 128;
  const float* xptr = X + (size_t)(xrow + l15) * LAT + kb + lk8;

  f32x4 acc[8];
#pragma unroll
  for (int f = 0; f < 8; ++f) acc[f] = (f32x4){0.f, 0.f, 0.f, 0.f};

  float4 xv[4][2];
#pragma unroll
  for (int s = 0; s < 4; ++s) {
    xv[s][0] = *(const float4*)(xptr + s * 32);
    xv[s][1] = *(const float4*)(xptr + s * 32 + 4);
  }
#pragma unroll
  for (int s = 0; s < 4; ++s) {
    const float vv[8] = {xv[s][0].x, xv[s][0].y, xv[s][0].z, xv[s][0].w,
                         xv[s][1].x, xv[s][1].y, xv[s][1].z, xv[s][1].w};
    bf16x8 bfr;
#pragma unroll
    for (int i = 0; i < 8; ++i) bfr[i] = (short)f2bf(vv[i]);
    const int k = kb + s * 32 + lk8;
#pragma unroll
    for (int f = 0; f < 8; ++f) {
      const bf16x8 afr = *(const bf16x8*)(W1T + (size_t)(f * 16 + l15) * LAT + k);
      acc[f] = __builtin_amdgcn_mfma_f32_16x16x32_bf16(afr, bfr, acc[f], 0, 0, 0);
    }
  }
  // acc[f][e] = partial H[row=l15][col=f*16+lq*4+e] over K chunk w.
#pragma unroll
  for (int f = 0; f < 8; ++f)
    *(f32x4*)&part[w][lq * 16 + l15][f * 4] = acc[f];
  __syncthreads();

  // combine: thread t -> row r = t>>4, cols cg..cg+7, cg = (t&15)*8
  const int r = tid >> 4;           // 0..15
  const int cg = (tid & 15) * 8;    // 0..120
  const int f = cg >> 4;            // frag
  const int lq0 = (cg >> 2) & 3;    // 0 or 2
  f32x4 h0 = *(const f32x4*)&part[0][lq0 * 16 + r][f * 4];
  f32x4 h1 = *(const f32x4*)&part[0][(lq0 + 1) * 16 + r][f * 4];
#pragma unroll
  for (int ww = 1; ww < 4; ++ww) {
    h0 += *(const f32x4*)&part[ww][lq0 * 16 + r][f * 4];
    h1 += *(const f32x4*)&part[ww][(lq0 + 1) * 16 + r][f * 4];
  }
  // store H bf16
  {
    ushort4 z0 = {f2bf(h0[0]), f2bf(h0[1]), f2bf(h0[2]), f2bf(h0[3])};
    ushort4 z1 = {f2bf(h1[0]), f2bf(h1[1]), f2bf(h1[2]), f2bf(h1[3])};
    unsigned short* hp = H + (size_t)(row0 + r) * HID + cg;
    *(ushort4*)hp = z0;
    *(ushort4*)(hp + 4) = z1;
  }
  __syncthreads();  // all part reads done; planes 0/1 now reusable for stats
  float(*sS)[132] = (float(*)[132]) & part[0][0][0];  // 16x132 fits in plane (8448 B)
  float(*sQ)[132] = (float(*)[132]) & part[1][0][0];
  *(f32x4*)&sS[r][cg] = h0;
  *(f32x4*)&sS[r][cg + 4] = h1;
  *(f32x4*)&sQ[r][cg] = h0 * h0;
  *(f32x4*)&sQ[r][cg + 4] = h1 * h1;
  __syncthreads();
  if (tid < HID) {
    float s = 0.f, q = 0.f;
#pragma unroll
    for (int rr = 0; rr < 16; ++rr) { s += sS[rr][tid]; q += sQ[rr][tid]; }
    float* pS = set1 ? pS1 + (size_t)b * HID : pS2 + (size_t)(b - nb1) * HID;
    float* pQ = set1 ? pQ1 + (size_t)b * HID : pQ2 + (size_t)(b - nb1) * HID;
    pS[tid] = s;
    pQ[tid] = q;
  }
}

// ---------------- finalize BN affine per set ----------------
__global__ __launch_bounds__(1024) void k_finalize(
    const float* __restrict__ pS1, const float* __restrict__ pQ1,
    const float* __restrict__ pS2, const float* __restrict__ pQ2,
    const float* __restrict__ gamma, const float* __restrict__ beta,
    float* __restrict__ sc1, float* __restrict__ sh1,
    float* __restrict__ sc2, float* __restrict__ sh2,
    int nb1, int nb2, float n1count, float n2count) {
  __shared__ float sA[8][HID], qA[8][HID], sB[2][HID], qB[2][HID];
  const int tid = threadIdx.x;
  const int col = tid & 127, chunk = tid >> 7;  // 0..7
  {
    const int len = nb1 >> 3;
    const int b0 = chunk * len;
    float s = 0.f, q = 0.f;
    for (int b = b0; b < b0 + len; ++b) {
      s += pS1[(size_t)b * HID + col];
      q += pQ1[(size_t)b * HID + col];
    }
    sA[chunk][col] = s;
    qA[chunk][col] = q;
  }
  if (chunk < 2) {
    const int len = nb2 >> 1;
    const int b0 = chunk * len;
    float s = 0.f, q = 0.f;
    for (int b = b0; b < b0 + len; ++b) {
      s += pS2[(size_t)b * HID + col];
      q += pQ2[(size_t)b * HID + col];
    }
    sB[chunk][col] = s;
    qB[chunk][col] = q;
  }
  __syncthreads();
  if (tid < 256) {
    const int c = tid & 127;
    const bool one = tid < 128;
    float s = 0.f, q = 0.f;
    if (one) {
#pragma unroll
      for (int r = 0; r < 8; ++r) { s += sA[r][c]; q += qA[r][c]; }
    } else {
      s = sB[0][c] + sB[1][c];
      q = qB[0][c] + qB[1][c];
    }
    const float n = one ? n1count : n2count;
    const float mean = s / n;
    const float var = q / n - mean * mean;
    const float rstd = rsqrtf(var + EPSV);
    const float scale = gamma[c] * rstd;
    const float shift = beta[c] - mean * scale;
    if (one) { sc1[c] = scale; sh1[c] = shift; }
    else     { sc2[c] = scale; sh2[c] = shift; }
  }
}

// ---------------- gemm2: 4 waves frag-split, Z(bf16) + f32 row norms ----------------
// wave w handles frags f = 2w, 2w+1 (cols w*32 .. w*32+31), full K=128.
__global__ __launch_bounds__(256) void k_gemm2(
    const unsigned short* __restrict__ H, int nx,
    const unsigned short* __restrict__ W2T,
    const float* __restrict__ sc1, const float* __restrict__ sh1,
    const float* __restrict__ sc2, const float* __restrict__ sh2,
    unsigned short* __restrict__ Z, float* __restrict__ nrm) {
  __shared__ float sN[4][16];
  const int tid = threadIdx.x, w = tid >> 6, lane = tid & 63;
  const int l15 = lane & 15, lq = lane >> 4, lk8 = lq * 8;
  const int row0 = (int)blockIdx.x * 16;
  const bool set1 = row0 < nx;
  const float* sc = set1 ? sc1 : sc2;
  const float* sh = set1 ? sh1 : sh2;
  const unsigned short* hptr = H + (size_t)(row0 + l15) * HID + lk8;
  f32x4 acc[2];
  acc[0] = (f32x4){0.f, 0.f, 0.f, 0.f};
  acc[1] = (f32x4){0.f, 0.f, 0.f, 0.f};
#pragma unroll
  for (int s = 0; s < 4; ++s) {
    const int k = s * 32 + lk8;
    const bf16x8 hv = *(const bf16x8*)(hptr + s * 32);
    const float4 c0 = *(const float4*)(sc + k);
    const float4 c1 = *(const float4*)(sc + k + 4);
    const float4 d0 = *(const float4*)(sh + k);
    const float4 d1 = *(const float4*)(sh + k + 4);
    const float cc[8] = {c0.x, c0.y, c0.z, c0.w, c1.x, c1.y, c1.z, c1.w};
    const float dd[8] = {d0.x, d0.y, d0.z, d0.w, d1.x, d1.y, d1.z, d1.w};
    bf16x8 bfr;
#pragma unroll
    for (int i = 0; i < 8; ++i) {
      const float a = fmaxf(fmaf(bf2f((unsigned short)hv[i]), cc[i], dd[i]), 0.f);
      bfr[i] = (short)f2bf(a);
    }
#pragma unroll
    for (int ff = 0; ff < 2; ++ff) {
      const int f = w * 2 + ff;
      const bf16x8 afr = *(const bf16x8*)(W2T + (size_t)(f * 16 + l15) * HID + k);
      acc[ff] = __builtin_amdgcn_mfma_f32_16x16x32_bf16(afr, bfr, acc[ff], 0, 0, 0);
    }
  }
  float rn = 0.f;
#pragma unroll
  for (int ff = 0; ff < 2; ++ff) {
    rn += acc[ff][0] * acc[ff][0] + acc[ff][1] * acc[ff][1] +
          acc[ff][2] * acc[ff][2] + acc[ff][3] * acc[ff][3];
    const int f = w * 2 + ff;
    ushort4 z4 = {f2bf(acc[ff][0]), f2bf(acc[ff][1]), f2bf(acc[ff][2]), f2bf(acc[ff][3])};
    *(ushort4*)(Z + (size_t)(row0 + l15) * HID + f * 16 + lq * 4) = z4;
  }
  rn += __shfl_xor(rn, 16, 64);
  rn += __shfl_xor(rn, 32, 64);
  if (lane < 16) sN[w][l15] = rn;
  __syncthreads();
  if (w == 0 && lane < 16)
    nrm[row0 + l15] = sN[0][l15] + sN[1][l15] + sN[2][l15] + sN[3][l15];
}

// ---------------- dist: D = n1[i] + n2[j] - 2 * Z1 @ Z2^T, float4 epilogue ----------------
__global__ __launch_bounds__(256) void k_dist(const unsigned short* __restrict__ Z1b,
                                              const unsigned short* __restrict__ Z2b,
                                              const float* __restrict__ n1,
                                              const float* __restrict__ n2,
                                              float* __restrict__ D, int NY) {
  const int tid = threadIdx.x;
  const int wid = tid >> 6, lane = tid & 63;
  const int wr = wid >> 1, wc = wid & 1;
  const int rowB = blockIdx.y * 128 + wr * 64;
  const int colB = blockIdx.x * 128 + wc * 64;
  const int l15 = lane & 15, lq = lane >> 4;
  const int lk = lq * 8;
  const unsigned short* Arow = Z1b + (size_t)(rowB + l15) * HID + lk;
  const unsigned short* Brow = Z2b + (size_t)(colB + l15) * HID + lk;
  f32x4 acc[4][4];
#pragma unroll
  for (int i = 0; i < 4; ++i)
#pragma unroll
    for (int j = 0; j < 4; ++j) acc[i][j] = (f32x4){0.f, 0.f, 0.f, 0.f};
#pragma unroll
  for (int s = 0; s < 4; ++s) {
    bf16x8 a[4], b[4];
#pragma unroll
    for (int i = 0; i < 4; ++i) a[i] = *(const bf16x8*)(Arow + (size_t)i * 16 * HID + s * 32);
#pragma unroll
    for (int j = 0; j < 4; ++j) b[j] = *(const bf16x8*)(Brow + (size_t)j * 16 * HID + s * 32);
#pragma unroll
    for (int i = 0; i < 4; ++i)
#pragma unroll
      for (int j = 0; j < 4; ++j)
        acc[i][j] = __builtin_amdgcn_mfma_f32_16x16x32_bf16(b[j], a[i], acc[i][j], 0, 0, 0);
  }
  const int cq = lq * 4;
  float na[4];
#pragma unroll
  for (int i = 0; i < 4; ++i) na[i] = n1[rowB + i * 16 + l15];
#pragma unroll
  for (int j = 0; j < 4; ++j) {
    const float4 nb = *(const float4*)(n2 + colB + j * 16 + cq);
#pragma unroll
    for (int i = 0; i < 4; ++i) {
      float4 o;
      o.x = na[i] + nb.x - 2.f * acc[i][j][0];
      o.y = na[i] + nb.y - 2.f * acc[i][j][1];
      o.z = na[i] + nb.z - 2.f * acc[i][j][2];
      o.w = na[i] + nb.w - 2.f * acc[i][j][3];
      *(float4*)(D + (size_t)(rowB + i * 16 + l15) * NY + colB + j * 16 + cq) = o;
    }
  }
}

extern "C" void kernel_launch(void* const* d_in, const int* in_sizes, int n_in,
                              void* d_out, int out_size, void* d_ws, size_t ws_size,
                              hipStream_t stream) {
  const float* variations = (const float*)d_in[0];
  const float* exemplar   = (const float*)d_in[1];
  const float* w1         = (const float*)d_in[2];
  const float* gamma      = (const float*)d_in[3];
  const float* beta       = (const float*)d_in[4];
  const float* w2         = (const float*)d_in[5];
  float* D = (float*)d_out;

  const int nx = in_sizes[0] / LAT;  // 8192
  const int ny = in_sizes[1] / LAT;  // 2048
  const int nrows = nx + ny;         // 10240
  const int nb1 = nx / 16;           // 512
  const int nb2 = ny / 16;           // 128
  const int nbb = nb1 + nb2;         // 640

  char* p = (char*)d_ws;
  unsigned short* Hb  = (unsigned short*)p; p += (size_t)nrows * HID * 2;
  unsigned short* Zb  = (unsigned short*)p; p += (size_t)nrows * HID * 2;
  unsigned short* W1T = (unsigned short*)p; p += (size_t)LAT * HID * 2;
  unsigned short* W2T = (unsigned short*)p; p += (size_t)HID * HID * 2;
  float* pS1 = (float*)p; p += (size_t)nb1 * HID * 4;
  float* pQ1 = (float*)p; p += (size_t)nb1 * HID * 4;
  float* pS2 = (float*)p; p += (size_t)nb2 * HID * 4;
  float* pQ2 = (float*)p; p += (size_t)nb2 * HID * 4;
  float* sc1 = (float*)p; p += HID * 4;
  float* sh1 = (float*)p; p += HID * 4;
  float* sc2 = (float*)p; p += HID * 4;
  float* sh2 = (float*)p; p += HID * 4;
  float* nrmAll = (float*)p; p += (size_t)nrows * 4;
  float* n1v = nrmAll;
  float* n2v = nrmAll + nx;
  unsigned short* Z1b = Zb;
  unsigned short* Z2b = Zb + (size_t)nx * HID;

  k_prep<<<20, 256, 0, stream>>>(w1, w2, W1T, W2T);
  k_gemm1<<<nbb, 256, 0, stream>>>(variations, exemplar, nx, W1T, Hb,
                                   pS1, pQ1, pS2, pQ2, nb1);
  k_finalize<<<1, 1024, 0, stream>>>(pS1, pQ1, pS2, pQ2, gamma, beta,
                                     sc1, sh1, sc2, sh2, nb1, nb2, (float)nx, (float)ny);
  k_gemm2<<<nbb, 256, 0, stream>>>(Hb, nx, W2T, sc1, sh1, sc2, sh2, Zb, nrmAll);
  dim3 dgrid(ny / 128, nx / 128);
  k_dist<<<dgrid, 256, 0, stream>>>(Z1b, Z2b, n1v, n2v, D, ny);
}